// Round 11
// baseline (140.736 us; speedup 1.0000x reference)
//
#include <hip/hip_runtime.h>
#include <hip/hip_bf16.h>
#include <math.h>

#define B_ 64
#define T_ 512
#define D_ 768
#define H_ 96
#define M_ (B_*T_)   // 32768 rows

typedef __attribute__((ext_vector_type(8))) short short8;
typedef __attribute__((ext_vector_type(4))) float f32x4;

__device__ __forceinline__ short f2bf(float f) {
  unsigned u = __float_as_uint(f);
  unsigned r = (u + 0x7FFFu + ((u >> 16) & 1u)) >> 16;   // RTNE
  return (short)r;
}

// ---------------------------------------------------------------------------
// Kernel 0: W -> bf16, transposed to [n][k] (n = mi*96+cc, 288 x 768).
// ---------------------------------------------------------------------------
__global__ __launch_bounds__(256) void wt_kernel(
    const float* __restrict__ Wq, const float* __restrict__ Wk,
    const float* __restrict__ Wv, short* __restrict__ wt)
{
  int id = blockIdx.x * 256 + threadIdx.x;     // 3*96*768 = 221184
  if (id >= 3*H_*D_) return;
  int n = id % 288;
  int k = id / 288;
  int mi = n / 96, cc = n % 96;
  const float* Wm = (mi == 0) ? Wq : ((mi == 1) ? Wk : Wv);
  wt[(size_t)n * D_ + k] = f2bf(Wm[(size_t)k * H_ + cc]);
}

// ---------------------------------------------------------------------------
// Kernel 1: QKV projection via MFMA bf16.
// Round-10 diagnosis: af[24] (96 VGPR) + acc[18] (72) > 128 allocated ->
// compiler spilled af to scratch (WRITE_SIZE 19->34 MB canary), MFMA loop
// latency-bound on scratch reloads.  Fix: (a) af8[8] per 8-step K-chunk
// (32 VGPR, 3 chunks); (b) 6 waves = 2 row-groups x 3 matrices, each wave
// owns ONE matrix (96 cols, acc[6]=24 VGPR) -> 3x less redundant LDS read
// of the W tile.  W tile (L2-resident) is the only LDS staging.
// ---------------------------------------------------------------------------
#define BKP 32
#define ASTR 36

__global__ __launch_bounds__(384) void qkv_mfma_kernel(
    const float* __restrict__ x, const short* __restrict__ wt,
    short* __restrict__ qb, short* __restrict__ kb, short* __restrict__ vtp)
{
  __shared__ short bs[2][288][ASTR];   // 41,472 B

  const int t    = threadIdx.x;
  const int row0 = blockIdx.x * 32;
  const int lane = t & 63;
  const int w    = t >> 6;        // 0..5
  const int mi   = w >> 1;        // matrix 0..2 (wave-uniform)
  const int wrg  = w & 1;         // row-group 0..1
  const int l15  = lane & 15;
  const int l4   = lane >> 4;
  const int swz  = (l4 ^ (l15 & 3)) * 8;   // read-side swizzled chunk offset

  // stage W K-tile (288 x 32 bf16), write-side chunk XOR swizzle.
  // 1152 short8 chunks / 384 threads = exactly 3 per thread.
  auto stageW = [&](int buf, int k0) {
    #pragma unroll
    for (int i = 0; i < 3; ++i) {
      int id = t + i * 384;
      int n = id >> 2, k8 = id & 3;
      short8 v = *reinterpret_cast<const short8*>(wt + (size_t)n * D_ + k0 + k8 * 8);
      *reinterpret_cast<short8*>(&bs[buf][n][(k8 ^ (n & 3)) * 8]) = v;
    }
  };

  f32x4 acc[6];
  #pragma unroll
  for (int ci = 0; ci < 6; ++ci) acc[ci] = (f32x4){0.f, 0.f, 0.f, 0.f};

  const float* xr = x + (size_t)(row0 + wrg * 16 + l15) * D_ + l4 * 8;

  stageW(0, 0);
  __syncthreads();

  for (int c = 0; c < 3; ++c) {          // 3 K-chunks of 8 steps (K=256 each)
    // A-frags for this chunk: wave's 16 rows, k in [c*256, c*256+256)
    short8 af8[8];
    #pragma unroll
    for (int s = 0; s < 8; ++s) {
      const float* src = xr + c * 256 + s * 32;
      float4 f0 = *reinterpret_cast<const float4*>(src);
      float4 f1 = *reinterpret_cast<const float4*>(src + 4);
      short8 v;
      v[0] = f2bf(f0.x); v[1] = f2bf(f0.y); v[2] = f2bf(f0.z); v[3] = f2bf(f0.w);
      v[4] = f2bf(f1.x); v[5] = f2bf(f1.y); v[6] = f2bf(f1.z); v[7] = f2bf(f1.w);
      af8[s] = v;
    }
    #pragma unroll
    for (int s = 0; s < 8; ++s) {        // static s -> af8[s] stays in regs
      int ks = c * 8 + s;
      int buf = s & 1;                   // (c*8+s)&1 == s&1
      if (ks + 1 < 24) stageW(buf ^ 1, (ks + 1) * BKP);
      #pragma unroll
      for (int ci = 0; ci < 6; ++ci) {
        short8 bfrag = *reinterpret_cast<const short8*>(
            &bs[buf][mi * 96 + ci * 16 + l15][swz]);
        acc[ci] = __builtin_amdgcn_mfma_f32_16x16x32_bf16(
            af8[s], bfrag, acc[ci], 0, 0, 0);
      }
      __syncthreads();
    }
  }

  // epilogue: frag ci: rows = row0 + wrg*16 + l4*4 + reg, col = mi*96 + ci*16 + l15
  const int rbase = row0 + wrg * 16 + l4 * 4;
  if (mi == 2) {
    int bb = rbase / T_, tl = rbase % T_;   // 4 tokens, same batch (4 | T)
    #pragma unroll
    for (int ci = 0; ci < 6; ++ci) {
      int cc = ci * 16 + l15;
      short4 pk;
      pk.x = f2bf(acc[ci][0]); pk.y = f2bf(acc[ci][1]);
      pk.z = f2bf(acc[ci][2]); pk.w = f2bf(acc[ci][3]);
      *reinterpret_cast<short4*>(vtp + ((size_t)bb * H_ + cc) * T_ + tl) = pk;
    }
  } else {
    short* Om = (mi == 0) ? qb : kb;
    #pragma unroll
    for (int ci = 0; ci < 6; ++ci) {
      int cc = ci * 16 + l15;
      #pragma unroll
      for (int reg = 0; reg < 4; ++reg)
        Om[(size_t)(rbase + reg) * H_ + cc] = f2bf(acc[ci][reg]);
    }
  }
}

// ---------------------------------------------------------------------------
// Kernel 2: causal flash attention via MFMA bf16 (unchanged from round 6).
// ---------------------------------------------------------------------------
#define QB 32
#define KVB 32
#define KSTR 104
#define VSTR 40
#define PSTR 40

__global__ __launch_bounds__(128) void attn_mfma_kernel(
    const short* __restrict__ qb, const short* __restrict__ kb,
    const short* __restrict__ vtp, float* __restrict__ out)
{
  __shared__ short ks[KVB][KSTR];     // 6656 B
  __shared__ short vs[H_][VSTR];      // 7680 B
  __shared__ short ps[2][16][PSTR];   // 2560 B

  const int t    = threadIdx.x;
  const int lane = t & 63;
  const int w    = t >> 6;            // 0..1
  const int l15  = lane & 15;
  const int l4   = lane >> 4;
  const int qi   = 15 - blockIdx.x;   // heavy blocks first
  const int b    = blockIdx.y;
  const int q0   = qi * QB;

  short8 qf[3];
  {
    const short* qbase = qb + ((size_t)(b * T_) + q0 + w * 16 + l15) * H_;
    #pragma unroll
    for (int f = 0; f < 3; ++f)
      qf[f] = *reinterpret_cast<const short8*>(qbase + f * 32 + l4 * 8);
  }

  f32x4 acc[6];
  #pragma unroll
  for (int c = 0; c < 6; ++c) acc[c] = (f32x4){0.f, 0.f, 0.f, 0.f};
  float m_r[4] = {-INFINITY, -INFINITY, -INFINITY, -INFINITY};
  float l_r[4] = {0.f, 0.f, 0.f, 0.f};
  const float scale = 0.10206207261596576f;   // 1/sqrt(96)

  const int jmax = q0 + QB;
  for (int j0 = 0; j0 < jmax; j0 += KVB) {
    __syncthreads();
    {  // stage K tile: 32 rows x 96 bf16
      int row = t >> 2, seg = t & 3;
      const short* src = kb + ((size_t)(b * T_) + j0 + row) * H_ + seg * 24;
      short* dst = &ks[row][seg * 24];
      *reinterpret_cast<short8*>(dst)      = *reinterpret_cast<const short8*>(src);
      *reinterpret_cast<short8*>(dst + 8)  = *reinterpret_cast<const short8*>(src + 8);
      *reinterpret_cast<short8*>(dst + 16) = *reinterpret_cast<const short8*>(src + 16);
    }
    {  // stage V tile: 96 h x 32 keys (pre-transposed in global)
      #pragma unroll
      for (int i = 0; i < 3; ++i) {
        int c = t + i * 128;
        int h = c >> 2, k8 = c & 3;
        *reinterpret_cast<short8*>(&vs[h][k8 * 8]) =
            *reinterpret_cast<const short8*>(vtp + ((size_t)b * H_ + h) * T_ + j0 + k8 * 8);
      }
    }
    __syncthreads();

    f32x4 sfr[2];
    sfr[0] = (f32x4){0.f,0.f,0.f,0.f};
    sfr[1] = (f32x4){0.f,0.f,0.f,0.f};
    #pragma unroll
    for (int ct = 0; ct < 2; ++ct)
      #pragma unroll
      for (int f = 0; f < 3; ++f) {
        short8 kf = *reinterpret_cast<const short8*>(&ks[ct * 16 + l15][f * 32 + l4 * 8]);
        sfr[ct] = __builtin_amdgcn_mfma_f32_16x16x32_bf16(qf[f], kf, sfr[ct], 0, 0, 0);
      }

    const int qrow = q0 + w * 16 + l4 * 4;   // +reg
    float p0[4], p1[4], fsc[4];
    #pragma unroll
    for (int reg = 0; reg < 4; ++reg) {
      float s0 = sfr[0][reg] * scale;
      float s1 = sfr[1][reg] * scale;
      if (j0 + l15      > qrow + reg) s0 = -INFINITY;
      if (j0 + l15 + 16 > qrow + reg) s1 = -INFINITY;
      float tm = fmaxf(s0, s1);
      #pragma unroll
      for (int o = 1; o < 16; o <<= 1) tm = fmaxf(tm, __shfl_xor(tm, o));
      float Mnew = fmaxf(m_r[reg], tm);
      p0[reg] = __expf(s0 - Mnew);
      p1[reg] = __expf(s1 - Mnew);
      float psum = p0[reg] + p1[reg];
      #pragma unroll
      for (int o = 1; o < 16; o <<= 1) psum += __shfl_xor(psum, o);
      fsc[reg] = __expf(m_r[reg] - Mnew);
      m_r[reg] = Mnew;
      l_r[reg] = l_r[reg] * fsc[reg] + psum;
    }
    #pragma unroll
    for (int c = 0; c < 6; ++c)
      #pragma unroll
      for (int reg = 0; reg < 4; ++reg) acc[c][reg] *= fsc[reg];

    #pragma unroll
    for (int reg = 0; reg < 4; ++reg) {
      ps[w][l4 * 4 + reg][l15]      = f2bf(p0[reg]);
      ps[w][l4 * 4 + reg][l15 + 16] = f2bf(p1[reg]);
    }
    short8 pa = *reinterpret_cast<const short8*>(&ps[w][l15][l4 * 8]);

    #pragma unroll
    for (int c = 0; c < 6; ++c) {
      short8 vf = *reinterpret_cast<const short8*>(&vs[c * 16 + l15][l4 * 8]);
      acc[c] = __builtin_amdgcn_mfma_f32_16x16x32_bf16(pa, vf, acc[c], 0, 0, 0);
    }
  }

  float inv[4];
  #pragma unroll
  for (int reg = 0; reg < 4; ++reg) inv[reg] = 1.f / l_r[reg];
  #pragma unroll
  for (int c = 0; c < 6; ++c) {
    #pragma unroll
    for (int reg = 0; reg < 4; ++reg) {
      size_t row = (size_t)(b * T_) + q0 + w * 16 + l4 * 4 + reg;
      out[row * H_ + c * 16 + l15] = acc[c][reg] * inv[reg];
    }
  }
}

extern "C" void kernel_launch(void* const* d_in, const int* in_sizes, int n_in,
                              void* d_out, int out_size, void* d_ws, size_t ws_size,
                              hipStream_t stream) {
  const float* x  = (const float*)d_in[0];
  const float* Wq = (const float*)d_in[1];
  const float* Wk = (const float*)d_in[2];
  const float* Wv = (const float*)d_in[3];

  short* wt  = (short*)d_ws;                               // 442,368 B
  short* qb  = (short*)((char*)d_ws + 524288);             // 6,291,456 B
  short* kb  = qb + (size_t)M_ * H_;
  short* vtp = kb + (size_t)M_ * H_;                       // [B][96][T]
  float* outp = (float*)d_out;

  hipLaunchKernelGGL(wt_kernel, dim3((3*H_*D_ + 255)/256), dim3(256), 0, stream,
                     Wq, Wk, Wv, wt);
  hipLaunchKernelGGL(qkv_mfma_kernel, dim3(M_/32), dim3(384), 0, stream,
                     x, wt, qb, kb, vtp);
  hipLaunchKernelGGL(attn_mfma_kernel, dim3(T_/QB, B_), dim3(128), 0, stream,
                     qb, kb, vtp, outp);
}

// Round 12
// 75.388 us; speedup vs baseline: 1.8668x; 1.8668x over previous
//
#include <hip/hip_runtime.h>
#include <hip/hip_bf16.h>
#include <math.h>

#define B_ 64
#define T_ 512
#define D_ 768
#define H_ 96
#define M_ (B_*T_)   // 32768 rows

typedef __attribute__((ext_vector_type(8))) short short8;
typedef __attribute__((ext_vector_type(4))) float f32x4;

__device__ __forceinline__ short f2bf(float f) {
  unsigned u = __float_as_uint(f);
  unsigned r = (u + 0x7FFFu + ((u >> 16) & 1u)) >> 16;   // RTNE
  return (short)r;
}

__device__ __forceinline__ void gl16(const void* g, void* l) {
  __builtin_amdgcn_global_load_lds(
      (const __attribute__((address_space(1))) unsigned*)g,
      (__attribute__((address_space(3))) unsigned*)l, 16, 0, 0);
}

// ---------------------------------------------------------------------------
// Kernel 0: W -> bf16, transposed to [n][k] (n = mi*96+cc, 288 x 768).
// ---------------------------------------------------------------------------
__global__ __launch_bounds__(256) void wt_kernel(
    const float* __restrict__ Wq, const float* __restrict__ Wk,
    const float* __restrict__ Wv, short* __restrict__ wt)
{
  int id = blockIdx.x * 256 + threadIdx.x;     // 3*96*768 = 221184
  if (id >= 3*H_*D_) return;
  int n = id % 288;
  int k = id / 288;
  int mi = n / 96, cc = n % 96;
  const float* Wm = (mi == 0) ? Wq : ((mi == 1) ? Wk : Wv);
  wt[(size_t)n * D_ + k] = f2bf(Wm[(size_t)k * H_ + cc]);
}

// ---------------------------------------------------------------------------
// Kernel 1: QKV projection, m97-style global_load_lds GEMM.
// Rounds 9-11 diagnosis: VGPR-round-trip staging serializes {load wait ->
// ds_write -> barrier drain} per K-step (MfmaUtil 5-8%).  Fix: stage A (x,
// fp32) and B (wt, bf16) straight to LDS with global_load_lds width-16 —
// the wave issues loads and computes immediately; only the end-of-step
// barrier waits.  2 blocks/CU so the drain overlaps the other block.
// Tiles: BM=64 x BK=32, 4 waves x (16 rows x 288 cols), acc[18]=72 VGPR.
// Bank fix (rule 21): linear LDS dest + XOR-pre-swizzled global source +
// same-XOR read.  A-frag fp32->bf16 on read (1 frag/step, amortized 18x).
// ---------------------------------------------------------------------------
#define BKP 32

__global__ __launch_bounds__(256) void qkv_mfma_kernel(
    const float* __restrict__ x, const short* __restrict__ wt,
    short* __restrict__ qb, short* __restrict__ kb, short* __restrict__ vtp)
{
  __shared__ float As[2][64][32];    // 16,384 B  (128 B/row = 8 x 16B slots)
  __shared__ short Bs[2][288][32];   // 36,864 B  ( 64 B/row = 4 x 16B slots)

  const int t    = threadIdx.x;
  const int row0 = blockIdx.x * 64;
  const int lane = t & 63;
  const int w    = t >> 6;        // 0..3: wave owns rows [row0+16w, +16)
  const int l15  = lane & 15;
  const int l4   = lane >> 4;

  // ---- staging: global_load_lds, 1 KB per wave-instr, linear LDS dest ----
  auto stageA = [&](int buf, int k0) {
    #pragma unroll
    for (int i = 0; i < 2; ++i) {
      int inst = w * 2 + i;                     // 0..7, 8 rows each
      int row  = inst * 8 + (lane >> 3);
      int c16  = (lane & 7) ^ ((lane >> 3) & 7);   // pre-swizzled source col
      const char* g = (const char*)(x + (size_t)(row0 + row) * D_ + k0) + c16 * 16;
      char* l = (char*)&As[buf][0][0] + inst * 1024 + lane * 16;
      gl16(g, l);
    }
  };
  auto stageB = [&](int buf, int k0) {
    #pragma unroll
    for (int i = 0; i < 5; ++i) {
      int inst = w + 4 * i;                     // 0..19, guard to 18
      if (inst < 18) {
        int row = inst * 16 + (lane >> 2);      // 0..287
        int c16 = (lane & 3) ^ ((lane >> 2) & 3);
        const char* g = (const char*)(wt + (size_t)row * D_ + k0) + c16 * 16;
        char* l = (char*)&Bs[buf][0][0] + inst * 1024 + lane * 16;
        gl16(g, l);
      }
    }
  };

  f32x4 acc[18];
  #pragma unroll
  for (int ci = 0; ci < 18; ++ci) acc[ci] = (f32x4){0.f, 0.f, 0.f, 0.f};

  stageA(0, 0);
  stageB(0, 0);
  __syncthreads();

  const int arow = w * 16 + l15;                // A row this lane reads
  const char* Abase = (const char*)&As[0][0][0];
  const char* Bbase = (const char*)&Bs[0][0][0];

  for (int ks = 0; ks < 24; ++ks) {
    int buf = ks & 1;
    if (ks + 1 < 24) { stageA(buf ^ 1, (ks + 1) * BKP); stageB(buf ^ 1, (ks + 1) * BKP); }

    // A-frag: fp32 swizzled read + convert (k = l4*8 .. +8)
    const char* ab = Abase + (size_t)buf * 8192 + arow * 128;
    float4 a0 = *reinterpret_cast<const float4*>(ab + (((l4 * 2 + 0) ^ (arow & 7)) * 16));
    float4 a1 = *reinterpret_cast<const float4*>(ab + (((l4 * 2 + 1) ^ (arow & 7)) * 16));
    short8 af;
    af[0] = f2bf(a0.x); af[1] = f2bf(a0.y); af[2] = f2bf(a0.z); af[3] = f2bf(a0.w);
    af[4] = f2bf(a1.x); af[5] = f2bf(a1.y); af[6] = f2bf(a1.z); af[7] = f2bf(a1.w);

    #pragma unroll
    for (int ci = 0; ci < 18; ++ci) {
      int brow = ci * 16 + l15;
      short8 bf = *reinterpret_cast<const short8*>(
          Bbase + (size_t)buf * 18432 + brow * 64 + ((l4 ^ (brow & 3)) * 16));
      acc[ci] = __builtin_amdgcn_mfma_f32_16x16x32_bf16(af, bf, acc[ci], 0, 0, 0);
    }
    __syncthreads();
  }

  // epilogue: acc[ci]: rows = row0 + w*16 + l4*4 + reg, col = ci*16 + l15
  const int rbase = row0 + w * 16 + l4 * 4;
  #pragma unroll
  for (int ci = 0; ci < 18; ++ci) {
    int mi = ci / 6;
    int cc = (ci % 6) * 16 + l15;
    if (mi == 2) {
      int bb = rbase / T_, tl = rbase % T_;     // 4 tokens, same batch (4 | T)
      short4 pk;
      pk.x = f2bf(acc[ci][0]); pk.y = f2bf(acc[ci][1]);
      pk.z = f2bf(acc[ci][2]); pk.w = f2bf(acc[ci][3]);
      *reinterpret_cast<short4*>(vtp + ((size_t)bb * H_ + cc) * T_ + tl) = pk;
    } else {
      short* Om = (mi == 0) ? qb : kb;
      #pragma unroll
      for (int reg = 0; reg < 4; ++reg)
        Om[(size_t)(rbase + reg) * H_ + cc] = f2bf(acc[ci][reg]);
    }
  }
}

// ---------------------------------------------------------------------------
// Kernel 2: causal flash attention via MFMA bf16 (unchanged from round 6).
// ---------------------------------------------------------------------------
#define QB 32
#define KVB 32
#define KSTR 104
#define VSTR 40
#define PSTR 40

__global__ __launch_bounds__(128) void attn_mfma_kernel(
    const short* __restrict__ qb, const short* __restrict__ kb,
    const short* __restrict__ vtp, float* __restrict__ out)
{
  __shared__ short ks[KVB][KSTR];     // 6656 B
  __shared__ short vs[H_][VSTR];      // 7680 B
  __shared__ short ps[2][16][PSTR];   // 2560 B

  const int t    = threadIdx.x;
  const int lane = t & 63;
  const int w    = t >> 6;            // 0..1
  const int l15  = lane & 15;
  const int l4   = lane >> 4;
  const int qi   = 15 - blockIdx.x;   // heavy blocks first
  const int b    = blockIdx.y;
  const int q0   = qi * QB;

  short8 qf[3];
  {
    const short* qbase = qb + ((size_t)(b * T_) + q0 + w * 16 + l15) * H_;
    #pragma unroll
    for (int f = 0; f < 3; ++f)
      qf[f] = *reinterpret_cast<const short8*>(qbase + f * 32 + l4 * 8);
  }

  f32x4 acc[6];
  #pragma unroll
  for (int c = 0; c < 6; ++c) acc[c] = (f32x4){0.f, 0.f, 0.f, 0.f};
  float m_r[4] = {-INFINITY, -INFINITY, -INFINITY, -INFINITY};
  float l_r[4] = {0.f, 0.f, 0.f, 0.f};
  const float scale = 0.10206207261596576f;   // 1/sqrt(96)

  const int jmax = q0 + QB;
  for (int j0 = 0; j0 < jmax; j0 += KVB) {
    __syncthreads();
    {  // stage K tile: 32 rows x 96 bf16
      int row = t >> 2, seg = t & 3;
      const short* src = kb + ((size_t)(b * T_) + j0 + row) * H_ + seg * 24;
      short* dst = &ks[row][seg * 24];
      *reinterpret_cast<short8*>(dst)      = *reinterpret_cast<const short8*>(src);
      *reinterpret_cast<short8*>(dst + 8)  = *reinterpret_cast<const short8*>(src + 8);
      *reinterpret_cast<short8*>(dst + 16) = *reinterpret_cast<const short8*>(src + 16);
    }
    {  // stage V tile: 96 h x 32 keys (pre-transposed in global)
      #pragma unroll
      for (int i = 0; i < 3; ++i) {
        int c = t + i * 128;
        int h = c >> 2, k8 = c & 3;
        *reinterpret_cast<short8*>(&vs[h][k8 * 8]) =
            *reinterpret_cast<const short8*>(vtp + ((size_t)b * H_ + h) * T_ + j0 + k8 * 8);
      }
    }
    __syncthreads();

    f32x4 sfr[2];
    sfr[0] = (f32x4){0.f,0.f,0.f,0.f};
    sfr[1] = (f32x4){0.f,0.f,0.f,0.f};
    #pragma unroll
    for (int ct = 0; ct < 2; ++ct)
      #pragma unroll
      for (int f = 0; f < 3; ++f) {
        short8 kf = *reinterpret_cast<const short8*>(&ks[ct * 16 + l15][f * 32 + l4 * 8]);
        sfr[ct] = __builtin_amdgcn_mfma_f32_16x16x32_bf16(qf[f], kf, sfr[ct], 0, 0, 0);
      }

    const int qrow = q0 + w * 16 + l4 * 4;   // +reg
    float p0[4], p1[4], fsc[4];
    #pragma unroll
    for (int reg = 0; reg < 4; ++reg) {
      float s0 = sfr[0][reg] * scale;
      float s1 = sfr[1][reg] * scale;
      if (j0 + l15      > qrow + reg) s0 = -INFINITY;
      if (j0 + l15 + 16 > qrow + reg) s1 = -INFINITY;
      float tm = fmaxf(s0, s1);
      #pragma unroll
      for (int o = 1; o < 16; o <<= 1) tm = fmaxf(tm, __shfl_xor(tm, o));
      float Mnew = fmaxf(m_r[reg], tm);
      p0[reg] = __expf(s0 - Mnew);
      p1[reg] = __expf(s1 - Mnew);
      float psum = p0[reg] + p1[reg];
      #pragma unroll
      for (int o = 1; o < 16; o <<= 1) psum += __shfl_xor(psum, o);
      fsc[reg] = __expf(m_r[reg] - Mnew);
      m_r[reg] = Mnew;
      l_r[reg] = l_r[reg] * fsc[reg] + psum;
    }
    #pragma unroll
    for (int c = 0; c < 6; ++c)
      #pragma unroll
      for (int reg = 0; reg < 4; ++reg) acc[c][reg] *= fsc[reg];

    #pragma unroll
    for (int reg = 0; reg < 4; ++reg) {
      ps[w][l4 * 4 + reg][l15]      = f2bf(p0[reg]);
      ps[w][l4 * 4 + reg][l15 + 16] = f2bf(p1[reg]);
    }
    short8 pa = *reinterpret_cast<const short8*>(&ps[w][l15][l4 * 8]);

    #pragma unroll
    for (int c = 0; c < 6; ++c) {
      short8 vf = *reinterpret_cast<const short8*>(&vs[c * 16 + l15][l4 * 8]);
      acc[c] = __builtin_amdgcn_mfma_f32_16x16x32_bf16(pa, vf, acc[c], 0, 0, 0);
    }
  }

  float inv[4];
  #pragma unroll
  for (int reg = 0; reg < 4; ++reg) inv[reg] = 1.f / l_r[reg];
  #pragma unroll
  for (int c = 0; c < 6; ++c) {
    #pragma unroll
    for (int reg = 0; reg < 4; ++reg) {
      size_t row = (size_t)(b * T_) + q0 + w * 16 + l4 * 4 + reg;
      out[row * H_ + c * 16 + l15] = acc[c][reg] * inv[reg];
    }
  }
}

extern "C" void kernel_launch(void* const* d_in, const int* in_sizes, int n_in,
                              void* d_out, int out_size, void* d_ws, size_t ws_size,
                              hipStream_t stream) {
  const float* x  = (const float*)d_in[0];
  const float* Wq = (const float*)d_in[1];
  const float* Wk = (const float*)d_in[2];
  const float* Wv = (const float*)d_in[3];

  short* wt  = (short*)d_ws;                               // 442,368 B
  short* qb  = (short*)((char*)d_ws + 524288);             // 6,291,456 B
  short* kb  = qb + (size_t)M_ * H_;
  short* vtp = kb + (size_t)M_ * H_;                       // [B][96][T]
  float* outp = (float*)d_out;

  hipLaunchKernelGGL(wt_kernel, dim3((3*H_*D_ + 255)/256), dim3(256), 0, stream,
                     Wq, Wk, Wv, wt);
  hipLaunchKernelGGL(qkv_mfma_kernel, dim3(M_/64), dim3(256), 0, stream,
                     x, wt, qb, kb, vtp);
  hipLaunchKernelGGL(attn_mfma_kernel, dim3(T_/QB, B_), dim3(128), 0, stream,
                     qb, kb, vtp, outp);
}